// Round 4
// baseline (450.452 us; speedup 1.0000x reference)
//
#include <hip/hip_runtime.h>

#define FLOW_DEPTH 8
#define TILE 64         // atoms per tile == lanes per wave; single-wave blocks
#define W_F4 18         // float4 per atom in w (72 floats = 288 B)
#define B_F4 6          // float4 per atom in b (24 floats = 96 B)
#define CH   65         // padded LDS chunk stride in float4 (64 data + 1 pad)
#define GRID 1024       // persistent blocks: 4 per CU (LDS 2*18.3 KiB = 37.4 KiB)

typedef const __attribute__((address_space(1))) void g_void;
typedef __attribute__((address_space(3))) void l_void;

// s_waitcnt with ONLY vmcnt constrained (expcnt=7, lgkmcnt=15 = unconstrained).
// gfx9 SIMM16: vmcnt[3:0]=bits3:0, expcnt=bits6:4, lgkmcnt=bits11:8, vmcnt[5:4]=bits15:14.
#define WAIT_VM(n) __builtin_amdgcn_s_waitcnt((((n) & 0xF) | ((((n) >> 4) & 0x3) << 14) | (0x7 << 4) | (0xF << 8)))

// Persistent double-buffered pipeline, one wave per block:
//   prologue: prefetch b/z(tile0) to regs, issue DMA(tile0 -> buf0)
//   loop:     prefetch b/z(next) to regs, issue DMA(next -> buf^1),
//             s_waitcnt vmcnt(18)   <- current tile drained, next 18 DMAs
//                                      stay IN FLIGHT across compute
//             compute current tile from LDS, store, swap buffers
// Fetch never idles: no vmcnt(0) on the steady-state path, no workgroup
// relaunch gaps (blocks are persistent, ~15 tiles each).
__global__ __launch_bounds__(TILE) void graphflow_kernel(
    const float* __restrict__ z_in,
    const float* __restrict__ w,
    const float* __restrict__ b,
    float* __restrict__ out,
    int n_atoms)
{
    __shared__ float4 sw[2][W_F4 * CH];   // 2 x 18.28 KiB (chunk k at [k*CH, k*CH+64))

    const int t = threadIdx.x;
    const int n_tiles = (n_atoms + TILE - 1) / TILE;
    int tile = blockIdx.x;
    if (tile >= n_tiles) return;

    auto issue_dma = [&](int tl, int bf) {
        const float4* gw = reinterpret_cast<const float4*>(w) + (size_t)tl * (TILE * W_F4);
#pragma unroll
        for (int k = 0; k < W_F4; ++k)
            __builtin_amdgcn_global_load_lds((g_void*)(gw + k * TILE + t),
                                             (l_void*)(&sw[bf][k * CH]), 16, 0, 0);
    };
    auto load_zb = [&](int tl, float4* brr, float& a0, float& a1, float& a2) {
        int a = tl * TILE + t;
        if (a < n_atoms) {
            const float4* gb = reinterpret_cast<const float4*>(b) + (size_t)a * B_F4;
#pragma unroll
            for (int j = 0; j < B_F4; ++j) brr[j] = gb[j];
            a0 = z_in[a * 3 + 0];
            a1 = z_in[a * 3 + 1];
            a2 = z_in[a * 3 + 2];
        }
    };

    bool cur_full = (tile * TILE + TILE <= n_atoms);
    float4 br_c[B_F4];
    float zc0 = 0.f, zc1 = 0.f, zc2 = 0.f;
    load_zb(tile, br_c, zc0, zc1, zc2);       // before DMA: keeps its wait <= vmcnt(18)
    if (cur_full) issue_dma(tile, 0);

    int buf = 0;
    for (;;) {
        const int nxt = tile + GRID;
        const bool has_next = (nxt < n_tiles);
        const bool nxt_full = has_next && (nxt * TILE + TILE <= n_atoms);

        float4 br_n[B_F4];
        float zn0 = 0.f, zn1 = 0.f, zn2 = 0.f;
        if (has_next) load_zb(nxt, br_n, zn0, zn1, zn2);   // issued BEFORE next DMA
        if (nxt_full) issue_dma(nxt, buf ^ 1);

        // Drain current tile's DMA; leave the 18 next-tile DMAs outstanding.
        if (nxt_full) WAIT_VM(18); else WAIT_VM(0);
        __builtin_amdgcn_sched_barrier(0);    // pin: no LDS read hoists above the wait

        const int a = tile * TILE + t;
        if (a < n_atoms) {
            float4 wr[W_F4];
            if (cur_full) {
#pragma unroll
                for (int j = 0; j < W_F4; ++j) {
                    int i = t * W_F4 + j;
                    wr[j] = sw[buf][i + (i >> 6)];
                }
            } else {
                // Partial (globally-last) tile: direct per-lane loads; no DMA
                // is outstanding in this case so compiler waits are harmless.
                const float4* gwa = reinterpret_cast<const float4*>(w) + (size_t)a * W_F4;
#pragma unroll
                for (int j = 0; j < W_F4; ++j) wr[j] = gwa[j];
            }

            const float* wf = reinterpret_cast<const float*>(wr);
            const float* bf2 = reinterpret_cast<const float*>(br_c);

            float z0 = zc0, z1 = zc1, z2 = zc2;
            float logdet = 0.0f;

#pragma unroll
            for (int d = 0; d < FLOW_DEPTH; ++d) {
                const float* W = wf + d * 9;
                float w00 = W[0], w01 = W[1], w02 = W[2];
                float w10 = W[3], w11 = W[4], w12 = W[5];
                float w20 = W[6], w21 = W[7], w22 = W[8];

                // D = |diag| + 0.1 ; log-det uses |0.1 + diag| (faithful to ref).
                float d0 = fabsf(w00) + 0.1f;
                float d1 = fabsf(w11) + 0.1f;
                float d2 = fabsf(w22) + 0.1f;
                // sum of 3 logs = log of |product|: one v_log_f32 not three.
                logdet += __logf(fabsf((0.1f + w00) * (0.1f + w11) * (0.1f + w22)));

                // M = L @ (D @ U), L = strict-lower + I, U = strict-upper + I
                float m01 = d0 * w01;
                float m02 = d0 * w02;
                float m12 = d1 * w12;
                float M00 = d0;
                float M01 = m01;
                float M02 = m02;
                float M10 = w10 * d0;
                float M11 = fmaf(w10, m01, d1);
                float M12 = fmaf(w10, m02, m12);
                float M20 = w20 * d0;
                float M21 = fmaf(w20, m01, w21 * d1);
                float M22 = fmaf(w20, m02, fmaf(w21, m12, d2));

                // z = z @ M + b[d]
                float t0 = fmaf(z0, M00, fmaf(z1, M10, fmaf(z2, M20, bf2[d * 3 + 0])));
                float t1 = fmaf(z0, M01, fmaf(z1, M11, fmaf(z2, M21, bf2[d * 3 + 1])));
                float t2 = fmaf(z0, M02, fmaf(z1, M12, fmaf(z2, M22, bf2[d * 3 + 2])));

                // z = z @ perms[d % 3]
                int p = d % 3;
                if (p == 0) {            // P_XY
                    z0 = t1; z1 = t0; z2 = t2;
                } else if (p == 1) {     // P_YZ
                    z0 = t2; z1 = t0; z2 = t1;
                } else {                 // P_XZ
                    z0 = t2; z1 = t1; z2 = t0;
                }
            }

            out[a * 3 + 0] = z0;
            out[a * 3 + 1] = z1;
            out[a * 3 + 2] = z2;
            out[(size_t)3 * n_atoms + a] = logdet;
        }

        if (!has_next) break;
        tile = nxt;
        cur_full = nxt_full;
        buf ^= 1;
#pragma unroll
        for (int j = 0; j < B_F4; ++j) br_c[j] = br_n[j];
        zc0 = zn0; zc1 = zn1; zc2 = zn2;
    }
}

extern "C" void kernel_launch(void* const* d_in, const int* in_sizes, int n_in,
                              void* d_out, int out_size, void* d_ws, size_t ws_size,
                              hipStream_t stream) {
    const float* z = (const float*)d_in[0];
    const float* w = (const float*)d_in[1];
    const float* b = (const float*)d_in[2];
    float* out = (float*)d_out;

    int n_atoms = in_sizes[0] / 3;  // z is [N,3]
    int n_tiles = (n_atoms + TILE - 1) / TILE;
    int grid = n_tiles < GRID ? n_tiles : GRID;

    hipLaunchKernelGGL(graphflow_kernel, dim3(grid), dim3(TILE), 0, stream,
                       z, w, b, out, n_atoms);
}